// Round 1
// 788.984 us; speedup vs baseline: 1.0822x; 1.0822x over previous
//
#include <hip/hip_runtime.h>
#include <cstdint>
#include <cstddef>

// Problem constants
#define B_DIM 16384
#define H_DIM 1024
#define K_DIM 2048   // IN + H (x|h concatenated along K)
#define N_DIM 4096   // 4*H (gate rows, permuted p = 4*h + g)

typedef _Float16 half8 __attribute__((ext_vector_type(8)));
typedef float floatx4 __attribute__((ext_vector_type(4)));

// Async global->LDS, 16B per lane. HW semantics: wave-uniform base + lane*16,
// so the LDS destination must be linear in lane order (it is, below).
__device__ __forceinline__ void async_copy16(const void* g, void* l) {
  __builtin_amdgcn_global_load_lds(
      (__attribute__((address_space(1))) void*)g,
      (__attribute__((address_space(3))) void*)l,
      16, 0, 0);
}

// ---------------------------------------------------------------------------
// Pack A = [x | h] as fp16, row-major [B_DIM][K_DIM]. 8 elems/thread.
// ---------------------------------------------------------------------------
__global__ __launch_bounds__(256) void pack_A_kernel(
    const float* __restrict__ x, const float* __restrict__ h,
    _Float16* __restrict__ A) {
  const size_t t = (size_t)blockIdx.x * 256 + threadIdx.x;
  const int row = (int)(t >> 8);          // K_DIM/8 = 256 chunks per row
  const int col = ((int)t & 255) * 8;
  const float* src = (col < H_DIM) ? (x + (size_t)row * H_DIM + col)
                                   : (h + (size_t)row * H_DIM + (col - H_DIM));
  const float4* s4 = (const float4*)src;
  float4 v0 = s4[0];
  float4 v1 = s4[1];
  half8 r = {(_Float16)v0.x, (_Float16)v0.y, (_Float16)v0.z, (_Float16)v0.w,
             (_Float16)v1.x, (_Float16)v1.y, (_Float16)v1.z, (_Float16)v1.w};
  *(half8*)(A + t * 8) = r;
}

// ---------------------------------------------------------------------------
// Pack W = [Wx | Wh] as fp16 with gate-interleaved row permutation:
// permuted row p = 4*h + g  <->  original row j = g*1024 + h.
// ---------------------------------------------------------------------------
__global__ __launch_bounds__(256) void pack_W_kernel(
    const float* __restrict__ Wx, const float* __restrict__ Wh,
    _Float16* __restrict__ Wp) {
  const size_t t = (size_t)blockIdx.x * 256 + threadIdx.x;
  const int p = (int)(t >> 8);
  const int k = ((int)t & 255) * 8;
  const int hidx = p >> 2;
  const int g = p & 3;
  const int j = g * H_DIM + hidx;
  const float* src = (k < H_DIM) ? (Wx + (size_t)j * H_DIM + k)
                                 : (Wh + (size_t)j * H_DIM + (k - H_DIM));
  const float4* s4 = (const float4*)src;
  float4 v0 = s4[0];
  float4 v1 = s4[1];
  half8 r = {(_Float16)v0.x, (_Float16)v0.y, (_Float16)v0.z, (_Float16)v0.w,
             (_Float16)v1.x, (_Float16)v1.y, (_Float16)v1.z, (_Float16)v1.w};
  *(half8*)(Wp + (size_t)p * K_DIM + k) = r;
}

// ---------------------------------------------------------------------------
// Fused GEMM (C = A @ Wp^T) + sLSTM pointwise epilogue.
// 256x256 tile, 512 threads (8 waves, 2Mx4N), counted-vmcnt 4-phase schedule
// (T3+T4), T2 chunk-XOR swizzle, T5 setprio, T1 XCD-aware block swizzle.
//
// LDS: double buffer, each buffer = K-tile PAIR (BK=32 each):
//   A[buf][tk]: [256][32] f16 = 16 KiB   (4 regions, bytes 0..65536)
//   B[buf][tk]: [256][32] f16 = 16 KiB   (4 regions, bytes 65536..131072)
// Iteration i computes K-tiles 2i,2i+1 from buf (i&1), stages 2i+2,2i+3 into
// the other buffer, 2 global_load_lds per phase. Steady-state invariant:
// 4 loads outstanding at iteration entry; vmcnt(4) at end of phases 1 and 3.
// ---------------------------------------------------------------------------
__global__ __launch_bounds__(512, 2) void slstm_gemm_fused(
    const _Float16* __restrict__ A,    // [B_DIM][K_DIM]
    const _Float16* __restrict__ Wp,   // [N_DIM][K_DIM], rows permuted p=4h+g
    const float* __restrict__ c_in,
    const float* __restrict__ n_in,
    const float* __restrict__ m_in,
    const float* __restrict__ bias,    // [4096], ORIGINAL order (g*1024+h)
    float* __restrict__ out)           // [4][B_DIM][H_DIM]: h,c,n,m
{
  __shared__ union SM {
    struct { _Float16 a[2][2][256 * 32]; _Float16 b[2][2][256 * 32]; } g; // 128 KiB
    float cbuf[64 * 268];                                                 // 67 KiB
  } sm;
  char* const lds = (char*)&sm;

  const int tid = threadIdx.x;

  // T1: bijective XCD swizzle (1024 blocks, 8 XCDs, 128/XCD), N fastest
  // within an XCD so A-panels (1 MiB) are reused out of the per-XCD L2.
  const int swz = ((int)blockIdx.x & 7) * 128 + ((int)blockIdx.x >> 3);
  const int b0 = (swz >> 4) * 256;   // M tile (batch rows)
  const int n0 = (swz & 15) * 256;   // N tile (permuted gate cols)

  const int lane = tid & 63;
  const int wave = tid >> 6;   // 0..7
  const int wm   = wave >> 2;  // 0..1: rows [wm*128, +128)
  const int wn   = wave & 3;   // 0..3: cols [wn*64, +64)
  const int l16  = lane & 15;
  const int quad = lane >> 4;

  // Staging source (per thread): row = tid>>2 (0..127, +128 for 2nd issue),
  // dest chunk c = tid&3; T2 swizzle: fetch global chunk c ^ ((row>>1)&3)
  // so LDS[row][c] = global[row][c ^ swz(row)] with linear LDS dest.
  const int srow = tid >> 2;
  const int gch  = (tid & 3) ^ ((tid >> 3) & 3);
  const _Float16* const Ag = A  + (size_t)(b0 + srow) * K_DIM + gch * 8;
  const _Float16* const Bg = Wp + (size_t)(n0 + srow) * K_DIM + gch * 8;

  // Fragment read chunk (same XOR): row = base16 + l16 -> swz = (l16>>1)&3.
  const int rsw = (quad ^ ((l16 >> 1) & 3)) * 8;   // f16 units

  floatx4 acc[8][4] = {};

#define LDS_A(buf, tk) (lds + (size_t)((((buf) * 2 + (tk)) * 16384)) + 16 * tid)
#define LDS_B(buf, tk) (lds + 65536 + (size_t)((((buf) * 2 + (tk)) * 16384)) + 16 * tid)
#define STAGE_A(buf, tk, kt) do {                        \
    const _Float16* g_ = Ag + (kt) * 32;                 \
    char* l_ = LDS_A(buf, tk);                           \
    async_copy16(g_, l_);                                \
    async_copy16(g_ + (size_t)128 * K_DIM, l_ + 8192);   \
  } while (0)
#define STAGE_B(buf, tk, kt) do {                        \
    const _Float16* g_ = Bg + (kt) * 32;                 \
    char* l_ = LDS_B(buf, tk);                           \
    async_copy16(g_, l_);                                \
    async_copy16(g_ + (size_t)128 * K_DIM, l_ + 8192);   \
  } while (0)
  // Barrier with compiler memory fence: C++ ds_reads must not be hoisted
  // across the vmcnt-wait -> barrier chain (cross-wave landing guarantee).
#define KBARRIER() asm volatile("s_barrier" ::: "memory")

  // Prologue: K-tiles 0,1 -> buffer 0 (8 loads/wave); wait K-tile 0 only.
  STAGE_A(0, 0, 0);
  STAGE_B(0, 0, 0);
  STAGE_A(0, 1, 1);
  STAGE_B(0, 1, 1);
  asm volatile("s_waitcnt vmcnt(4)" ::: "memory");
  KBARRIER();

#pragma unroll 2
  for (int it = 0; it < 32; ++it) {
    const int cur = it & 1;
    const int nxt = cur ^ 1;
    const int ks  = it * 2 + 2;        // K-tile pair staged this iteration
    const bool notlast = (it < 31);
#pragma unroll
    for (int p = 0; p < 4; ++p) {      // phase = (tk, mh)
      const int tk = p >> 1;
      const int mh = p & 1;
      const _Float16* As_ =
          (const _Float16*)(lds + (size_t)((cur * 2 + tk) * 16384));
      const _Float16* Bs_ =
          (const _Float16*)(lds + 65536 + (size_t)((cur * 2 + tk) * 16384));
      half8 af[4], bf[4];
#pragma unroll
      for (int a = 0; a < 4; ++a)
        af[a] = *(const half8*)(As_ + (wm * 128 + mh * 64 + a * 16 + l16) * 32 + rsw);
#pragma unroll
      for (int b = 0; b < 4; ++b)
        bf[b] = *(const half8*)(Bs_ + (wn * 64 + b * 16 + l16) * 32 + rsw);
      if (notlast) {
        if      (p == 0) STAGE_A(nxt, 0, ks);
        else if (p == 1) STAGE_B(nxt, 0, ks);
        else if (p == 2) STAGE_A(nxt, 1, ks + 1);
        else             STAGE_B(nxt, 1, ks + 1);
      }
      KBARRIER();
      __builtin_amdgcn_s_setprio(1);
#pragma unroll
      for (int a = 0; a < 4; ++a)
#pragma unroll
        for (int b = 0; b < 4; ++b)
          acc[mh * 4 + a][b] = __builtin_amdgcn_mfma_f32_16x16x32_f16(
              af[a], bf[b], acc[mh * 4 + a][b], 0, 0, 0);
      __builtin_amdgcn_s_setprio(0);
      if (p == 1) {
        if (notlast) asm volatile("s_waitcnt vmcnt(4)" ::: "memory");
        else         asm volatile("s_waitcnt vmcnt(0)" ::: "memory");
      } else if (p == 3) {
        if (notlast) asm volatile("s_waitcnt vmcnt(4)" ::: "memory");
      }
      KBARRIER();
    }
  }

  // -------------------------------------------------------------------------
  // Fused epilogue. C/D layout: col = lane&15, row = quad*4 + reg.
  // 4 phases of 64 rows through a [64][268] f32 LDS buffer (union with tiles;
  // no gload_lds in flight here). Permuted cols: float4 at col 4*hh holds
  // (i_t, f_t, z_t, o_t) for h = 64*(n0/256)*... = (n0>>2)+hh.
  // -------------------------------------------------------------------------
  const size_t BH = (size_t)B_DIM * H_DIM;
  const int hh = tid & 63;
  const int rb = tid >> 6;
  const int hg = (n0 >> 2) + hh;
  const float bi  = bias[hg];
  const float bfv = bias[H_DIM + hg];
  const float bz  = bias[2 * H_DIM + hg];
  const float bo  = bias[3 * H_DIM + hg];

#pragma unroll
  for (int ph = 0; ph < 4; ++ph) {
    if (wm == (ph >> 1)) {
      const int fb = (ph & 1) * 4;
#pragma unroll
      for (int a = 0; a < 4; ++a)
#pragma unroll
        for (int j = 0; j < 4; ++j)
#pragma unroll
          for (int r = 0; r < 4; ++r)
            sm.cbuf[(a * 16 + quad * 4 + r) * 268 + wn * 64 + j * 16 + l16] =
                acc[fb + a][j][r];
    }
    __syncthreads();

#pragma unroll
    for (int itr = 0; itr < 8; ++itr) {
      const int rl = itr * 8 + rb;             // local row in this 64-row phase
      const int bg = b0 + ph * 64 + rl;        // global batch row
      floatx4 gv = *(const floatx4*)&sm.cbuf[rl * 268 + hh * 4];
      const size_t idx = (size_t)bg * H_DIM + hg;

      const float it_ = gv.x + bi;
      const float ft_ = gv.y + bfv;
      float       zt_ = gv.z + bz;
      const float ot_ = gv.w + bo;

      const float mo = m_in[idx];
      const float fm = ft_ + mo;
      const float mn = fmaxf(fm, it_);
      const float fg = __expf(fm - mn);        // args <= 0: no overflow
      const float ig = __expf(it_ - mn);
      zt_ = fminf(fmaxf(zt_, -30.0f), 30.0f);
      const float e2 = __expf(2.0f * zt_);
      const float zg = (e2 - 1.0f) / (e2 + 1.0f);    // tanh
      const float og = 1.0f / (1.0f + __expf(-ot_)); // sigmoid
      const float cn = fg * c_in[idx] + ig * zg;
      const float nn = fg * n_in[idx] + ig;
      const float hn = og * (cn / fmaxf(fabsf(nn), 1.0f));

      out[idx]          = hn;
      out[BH + idx]     = cn;
      out[2 * BH + idx] = nn;
      out[3 * BH + idx] = mn;
    }
    __syncthreads();   // before next phase overwrites cbuf
  }
}

// ---------------------------------------------------------------------------
extern "C" void kernel_launch(void* const* d_in, const int* in_sizes, int n_in,
                              void* d_out, int out_size, void* d_ws, size_t ws_size,
                              hipStream_t stream) {
  (void)in_sizes; (void)n_in; (void)out_size; (void)ws_size;
  const float* x   = (const float*)d_in[0];
  const float* h   = (const float*)d_in[1];
  const float* c   = (const float*)d_in[2];
  const float* n   = (const float*)d_in[3];
  const float* m   = (const float*)d_in[4];
  const float* Wxw = (const float*)d_in[5];
  const float* Whw = (const float*)d_in[6];
  const float* Whb = (const float*)d_in[7];

  // Workspace layout: A fp16 [16384][2048] (64 MiB) + Wp fp16 [4096][2048] (16 MiB)
  _Float16* A  = (_Float16*)d_ws;
  _Float16* Wp = (_Float16*)((char*)d_ws + (size_t)B_DIM * K_DIM * sizeof(_Float16));

  pack_A_kernel<<<(B_DIM * (K_DIM / 8)) / 256, 256, 0, stream>>>(x, h, A);
  pack_W_kernel<<<(N_DIM * (K_DIM / 8)) / 256, 256, 0, stream>>>(Wxw, Whw, Wp);

  // 64 M-tiles x 16 N-tiles = 1024 blocks, XCD-swizzled in-kernel.
  slstm_gemm_fused<<<1024, 512, 0, stream>>>(A, Wp, c, n, m, Whb, (float*)d_out);
}

// Round 2
// 774.993 us; speedup vs baseline: 1.1017x; 1.0181x over previous
//
#include <hip/hip_runtime.h>
#include <cstdint>
#include <cstddef>

// Problem constants
#define B_DIM 16384
#define H_DIM 1024
#define K_DIM 2048   // IN + H (x|h concatenated along K)
#define N_DIM 4096   // 4*H (gate rows, permuted p = 4*h + g)

typedef _Float16 half8 __attribute__((ext_vector_type(8)));
typedef float floatx4 __attribute__((ext_vector_type(4)));

// Async global->LDS, 16B per lane. HW semantics: wave-uniform base + lane*16,
// so the LDS destination must be linear in lane order (it is, below).
__device__ __forceinline__ void async_copy16(const void* g, void* l) {
  __builtin_amdgcn_global_load_lds(
      (__attribute__((address_space(1))) void*)g,
      (__attribute__((address_space(3))) void*)l,
      16, 0, 0);
}

// ---------------------------------------------------------------------------
// Pack A = [x | h] as fp16, row-major [B_DIM][K_DIM]. 8 elems/thread.
// ---------------------------------------------------------------------------
__global__ __launch_bounds__(256) void pack_A_kernel(
    const float* __restrict__ x, const float* __restrict__ h,
    _Float16* __restrict__ A) {
  const size_t t = (size_t)blockIdx.x * 256 + threadIdx.x;
  const int row = (int)(t >> 8);          // K_DIM/8 = 256 chunks per row
  const int col = ((int)t & 255) * 8;
  const float* src = (col < H_DIM) ? (x + (size_t)row * H_DIM + col)
                                   : (h + (size_t)row * H_DIM + (col - H_DIM));
  const float4* s4 = (const float4*)src;
  float4 v0 = s4[0];
  float4 v1 = s4[1];
  half8 r = {(_Float16)v0.x, (_Float16)v0.y, (_Float16)v0.z, (_Float16)v0.w,
             (_Float16)v1.x, (_Float16)v1.y, (_Float16)v1.z, (_Float16)v1.w};
  *(half8*)(A + t * 8) = r;
}

// ---------------------------------------------------------------------------
// Pack W = [Wx | Wh] as fp16 with gate-interleaved row permutation:
// permuted row p = 4*h + g  <->  original row j = g*1024 + h.
// ---------------------------------------------------------------------------
__global__ __launch_bounds__(256) void pack_W_kernel(
    const float* __restrict__ Wx, const float* __restrict__ Wh,
    _Float16* __restrict__ Wp) {
  const size_t t = (size_t)blockIdx.x * 256 + threadIdx.x;
  const int p = (int)(t >> 8);
  const int k = ((int)t & 255) * 8;
  const int hidx = p >> 2;
  const int g = p & 3;
  const int j = g * H_DIM + hidx;
  const float* src = (k < H_DIM) ? (Wx + (size_t)j * H_DIM + k)
                                 : (Wh + (size_t)j * H_DIM + (k - H_DIM));
  const float4* s4 = (const float4*)src;
  float4 v0 = s4[0];
  float4 v1 = s4[1];
  half8 r = {(_Float16)v0.x, (_Float16)v0.y, (_Float16)v0.z, (_Float16)v0.w,
             (_Float16)v1.x, (_Float16)v1.y, (_Float16)v1.z, (_Float16)v1.w};
  *(half8*)(Wp + (size_t)p * K_DIM + k) = r;
}

// ---------------------------------------------------------------------------
// Fused GEMM (C = A @ Wp^T) + sLSTM pointwise epilogue.
// 256x256 tile, 512 threads (8 waves, 2Mx4N), counted-vmcnt 4-phase schedule
// (T3+T4), T2 chunk-XOR swizzle, T5 setprio, T1 XCD-aware block swizzle.
//
// Round-2 fix: K-loop barriers are the __builtin_amdgcn_s_barrier() BUILTIN
// (no "memory"-clobber asm). An asm with a memory clobber may read LDS, so
// SIInsertWaitcnts drains vmcnt(0) before it (global_load_lds writes LDS) --
// that silently degraded the counted-vmcnt pipeline to a drain-per-phase
// schedule. Compile-time ordering is now provided by sched_barrier(0)
// immediately after each barrier/wait instead of memory clobbers.
//
// LDS: double buffer, each buffer = K-tile PAIR (BK=32 each):
//   A[buf][tk]: [256][32] f16 = 16 KiB   (4 regions, bytes 0..65536)
//   B[buf][tk]: [256][32] f16 = 16 KiB   (4 regions, bytes 65536..131072)
// Iteration i computes K-tiles 2i,2i+1 from buf (i&1), stages 2i+2,2i+3 into
// the other buffer, 2 global_load_lds per phase. Steady-state invariant:
// 4 loads outstanding at iteration entry; vmcnt(4) at end of phases 1 and 3.
// ---------------------------------------------------------------------------
__global__ __launch_bounds__(512, 2) void slstm_gemm_fused(
    const _Float16* __restrict__ A,    // [B_DIM][K_DIM]
    const _Float16* __restrict__ Wp,   // [N_DIM][K_DIM], rows permuted p=4h+g
    const float* __restrict__ c_in,
    const float* __restrict__ n_in,
    const float* __restrict__ m_in,
    const float* __restrict__ bias,    // [4096], ORIGINAL order (g*1024+h)
    float* __restrict__ out)           // [4][B_DIM][H_DIM]: h,c,n,m
{
  __shared__ union SM {
    struct { _Float16 a[2][2][256 * 32]; _Float16 b[2][2][256 * 32]; } g; // 128 KiB
    float cbuf[64 * 268];                                                 // 67 KiB
  } sm;
  char* const lds = (char*)&sm;

  const int tid = threadIdx.x;

  // T1: bijective XCD swizzle (1024 blocks, 8 XCDs, 128/XCD), N fastest
  // within an XCD so A-panels (1 MiB) are reused out of the per-XCD L2.
  const int swz = ((int)blockIdx.x & 7) * 128 + ((int)blockIdx.x >> 3);
  const int b0 = (swz >> 4) * 256;   // M tile (batch rows)
  const int n0 = (swz & 15) * 256;   // N tile (permuted gate cols)

  const int lane = tid & 63;
  const int wave = tid >> 6;   // 0..7
  const int wm   = wave >> 2;  // 0..1: rows [wm*128, +128)
  const int wn   = wave & 3;   // 0..3: cols [wn*64, +64)
  const int l16  = lane & 15;
  const int quad = lane >> 4;

  // Staging source (per thread): row = tid>>2 (0..127, +128 for 2nd issue),
  // dest chunk c = tid&3; T2 swizzle: fetch global chunk c ^ ((row>>1)&3)
  // so LDS[row][c] = global[row][c ^ swz(row)] with linear LDS dest.
  const int srow = tid >> 2;
  const int gch  = (tid & 3) ^ ((tid >> 3) & 3);
  const _Float16* const Ag = A  + (size_t)(b0 + srow) * K_DIM + gch * 8;
  const _Float16* const Bg = Wp + (size_t)(n0 + srow) * K_DIM + gch * 8;

  // Fragment read chunk (same XOR): row = base16 + l16 -> swz = (l16>>1)&3.
  const int rsw = (quad ^ ((l16 >> 1) & 3)) * 8;   // f16 units

  floatx4 acc[8][4] = {};

#define LDS_A(buf, tk) (lds + (size_t)((((buf) * 2 + (tk)) * 16384)) + 16 * tid)
#define LDS_B(buf, tk) (lds + 65536 + (size_t)((((buf) * 2 + (tk)) * 16384)) + 16 * tid)
#define STAGE_A(buf, tk, kt) do {                        \
    const _Float16* g_ = Ag + (kt) * 32;                 \
    char* l_ = LDS_A(buf, tk);                           \
    async_copy16(g_, l_);                                \
    async_copy16(g_ + (size_t)128 * K_DIM, l_ + 8192);   \
  } while (0)
#define STAGE_B(buf, tk, kt) do {                        \
    const _Float16* g_ = Bg + (kt) * 32;                 \
    char* l_ = LDS_B(buf, tk);                           \
    async_copy16(g_, l_);                                \
    async_copy16(g_ + (size_t)128 * K_DIM, l_ + 8192);   \
  } while (0)
  // Builtin barrier (no memory clobber -> no forced vmcnt drain) + a full
  // scheduling fence so the compiler cannot move LDS reads/writes across it.
#define KBARRIER() do {                       \
    __builtin_amdgcn_s_barrier();             \
    __builtin_amdgcn_sched_barrier(0);        \
  } while (0)
#define VM_WAIT(n) do {                                   \
    asm volatile("s_waitcnt vmcnt(" #n ")");              \
    __builtin_amdgcn_sched_barrier(0);                    \
  } while (0)

  // Prologue: K-tiles 0,1 -> buffer 0 (8 loads/wave); wait K-tile 0 only.
  STAGE_A(0, 0, 0);
  STAGE_B(0, 0, 0);
  STAGE_A(0, 1, 1);
  STAGE_B(0, 1, 1);
  VM_WAIT(4);
  KBARRIER();

#pragma unroll 2
  for (int it = 0; it < 32; ++it) {
    const int cur = it & 1;
    const int nxt = cur ^ 1;
    const int ks  = it * 2 + 2;        // K-tile pair staged this iteration
    const bool notlast = (it < 31);
#pragma unroll
    for (int p = 0; p < 4; ++p) {      // phase = (tk, mh)
      const int tk = p >> 1;
      const int mh = p & 1;
      const _Float16* As_ =
          (const _Float16*)(lds + (size_t)((cur * 2 + tk) * 16384));
      const _Float16* Bs_ =
          (const _Float16*)(lds + 65536 + (size_t)((cur * 2 + tk) * 16384));
      half8 af[4], bf[4];
#pragma unroll
      for (int a = 0; a < 4; ++a)
        af[a] = *(const half8*)(As_ + (wm * 128 + mh * 64 + a * 16 + l16) * 32 + rsw);
#pragma unroll
      for (int b = 0; b < 4; ++b)
        bf[b] = *(const half8*)(Bs_ + (wn * 64 + b * 16 + l16) * 32 + rsw);
      if (notlast) {
        if      (p == 0) STAGE_A(nxt, 0, ks);
        else if (p == 1) STAGE_B(nxt, 0, ks);
        else if (p == 2) STAGE_A(nxt, 1, ks + 1);
        else             STAGE_B(nxt, 1, ks + 1);
      }
      KBARRIER();
      __builtin_amdgcn_s_setprio(1);
#pragma unroll
      for (int a = 0; a < 4; ++a)
#pragma unroll
        for (int b = 0; b < 4; ++b)
          acc[mh * 4 + a][b] = __builtin_amdgcn_mfma_f32_16x16x32_f16(
              af[a], bf[b], acc[mh * 4 + a][b], 0, 0, 0);
      __builtin_amdgcn_s_setprio(0);
      if (p == 1) {
        if (notlast) { VM_WAIT(4); } else { VM_WAIT(0); }
      } else if (p == 3) {
        if (notlast) { VM_WAIT(4); }
      }
      KBARRIER();
    }
  }

  // -------------------------------------------------------------------------
  // Fused epilogue. C/D layout: col = lane&15, row = quad*4 + reg.
  // 4 phases of 64 rows through a [64][268] f32 LDS buffer (union with tiles;
  // all gload_lds drained by the vmcnt(0) in the last iteration). Permuted
  // cols: float4 at col 4*hh holds (i_t, f_t, z_t, o_t) for h = (n0>>2)+hh.
  // -------------------------------------------------------------------------
  const size_t BH = (size_t)B_DIM * H_DIM;
  const int hh = tid & 63;
  const int rb = tid >> 6;
  const int hg = (n0 >> 2) + hh;
  const float bi  = bias[hg];
  const float bfv = bias[H_DIM + hg];
  const float bz  = bias[2 * H_DIM + hg];
  const float bo  = bias[3 * H_DIM + hg];

#pragma unroll
  for (int ph = 0; ph < 4; ++ph) {
    if (wm == (ph >> 1)) {
      const int fb = (ph & 1) * 4;
#pragma unroll
      for (int a = 0; a < 4; ++a)
#pragma unroll
        for (int j = 0; j < 4; ++j)
#pragma unroll
          for (int r = 0; r < 4; ++r)
            sm.cbuf[(a * 16 + quad * 4 + r) * 268 + wn * 64 + j * 16 + l16] =
                acc[fb + a][j][r];
    }
    __syncthreads();

#pragma unroll
    for (int itr = 0; itr < 8; ++itr) {
      const int rl = itr * 8 + rb;             // local row in this 64-row phase
      const int bg = b0 + ph * 64 + rl;        // global batch row
      floatx4 gv = *(const floatx4*)&sm.cbuf[rl * 268 + hh * 4];
      const size_t idx = (size_t)bg * H_DIM + hg;

      const float it_ = gv.x + bi;
      const float ft_ = gv.y + bfv;
      float       zt_ = gv.z + bz;
      const float ot_ = gv.w + bo;

      const float mo = m_in[idx];
      const float fm = ft_ + mo;
      const float mn = fmaxf(fm, it_);
      const float fg = __expf(fm - mn);        // args <= 0: no overflow
      const float ig = __expf(it_ - mn);
      zt_ = fminf(fmaxf(zt_, -30.0f), 30.0f);
      const float e2 = __expf(2.0f * zt_);
      const float zg = (e2 - 1.0f) / (e2 + 1.0f);    // tanh
      const float og = 1.0f / (1.0f + __expf(-ot_)); // sigmoid
      const float cn = fg * c_in[idx] + ig * zg;
      const float nn = fg * n_in[idx] + ig;
      const float hn = og * (cn / fmaxf(fabsf(nn), 1.0f));

      out[idx]          = hn;
      out[BH + idx]     = cn;
      out[2 * BH + idx] = nn;
      out[3 * BH + idx] = mn;
    }
    __syncthreads();   // before next phase overwrites cbuf
  }
}

// ---------------------------------------------------------------------------
extern "C" void kernel_launch(void* const* d_in, const int* in_sizes, int n_in,
                              void* d_out, int out_size, void* d_ws, size_t ws_size,
                              hipStream_t stream) {
  (void)in_sizes; (void)n_in; (void)out_size; (void)ws_size;
  const float* x   = (const float*)d_in[0];
  const float* h   = (const float*)d_in[1];
  const float* c   = (const float*)d_in[2];
  const float* n   = (const float*)d_in[3];
  const float* m   = (const float*)d_in[4];
  const float* Wxw = (const float*)d_in[5];
  const float* Whw = (const float*)d_in[6];
  const float* Whb = (const float*)d_in[7];

  // Workspace layout: A fp16 [16384][2048] (64 MiB) + Wp fp16 [4096][2048] (16 MiB)
  _Float16* A  = (_Float16*)d_ws;
  _Float16* Wp = (_Float16*)((char*)d_ws + (size_t)B_DIM * K_DIM * sizeof(_Float16));

  pack_A_kernel<<<(B_DIM * (K_DIM / 8)) / 256, 256, 0, stream>>>(x, h, A);
  pack_W_kernel<<<(N_DIM * (K_DIM / 8)) / 256, 256, 0, stream>>>(Wxw, Whw, Wp);

  // 64 M-tiles x 16 N-tiles = 1024 blocks, XCD-swizzled in-kernel.
  slstm_gemm_fused<<<1024, 512, 0, stream>>>(A, Wp, c, n, m, Whb, (float*)d_out);
}